// Round 6
// baseline (136.670 us; speedup 1.0000x reference)
//
#include <hip/hip_runtime.h>

typedef _Float16 half4 __attribute__((ext_vector_type(4)));
typedef float f32x4 __attribute__((ext_vector_type(4)));

#define NB 8
#define ND 32
#define NHW (512*512)
#define NK 16
#define IGN 255

// per-image stats workspace layout (floats)
#define WS_S   1088
#define O_CNT  0      // counts[16]
#define O_VPIX 16     // # of valid (mask & !=IGN) pixels
#define O_SUM  32     // sums[16*32], index = k*32 + d
#define O_PULL 1056   // pull partial sums[16]

#define IDP_OFF 65536          // byte offset of packed-id region in ws

// accum: 1024 blocks, each 16 tiles of 128 px (2048 contiguous px)
#define ATPB 256
#define ABLK 128
#define TILE 128
#define NTILES 16

// pull config
#define PTPB 256
#define PCHUNKS 256
#define PPIX (NHW / PCHUNKS)   // 1024

__global__ __launch_bounds__(256) void k_zero(float* __restrict__ ws) {
    int i = blockIdx.x * blockDim.x + threadIdx.x;
    if (i < NB * WS_S) ws[i] = 0.f;
}

// Pass 1: staged streaming + MFMA one-hot segment-sum.
// LDS: unpadded rows + XOR swizzle (swizzled global src, swizzled LDS read).
__global__ __launch_bounds__(ATPB) void k_accum(const float* __restrict__ pred,
                                                const int* __restrict__ inst,
                                                const unsigned char* __restrict__ msk,
                                                float* __restrict__ ws,
                                                unsigned char* __restrict__ idp) {
    __shared__ __align__(16) float buf[2][ND][TILE];   // 32 KB -> 4 blocks/CU
    __shared__ float lcnt[2][NK + 1];
    const int tid = threadIdx.x;
    const int w = tid >> 6, l = tid & 63;
    const int dgrp = w & 1;        // d-group: rows [16*dgrp, 16*dgrp+16)
    const int phalf = w >> 1;      // 64-px half of the 128-px tile
    const int b = blockIdx.y, chunk = blockIdx.x;

    if (tid < 2 * (NK + 1)) ((float*)lcnt)[tid] = 0.f;

    const size_t img = (size_t)b * NHW;
    const float* pb = pred + (size_t)b * ND * NHW;
    const int base0 = chunk * (NTILES * TILE);

    // stage: lane l covers row r = 8w+2q+(l>>5), 16B-slot s = l&31 which holds
    // logical col-chunk s ^ (r&7)  (inverse-swizzled source, linear LDS dst)
#define STAGE(CUR, T)                                                          \
    {                                                                          \
        const int tb_ = base0 + (T) * TILE;                                    \
        _Pragma("unroll")                                                      \
        for (int q_ = 0; q_ < 4; ++q_) {                                       \
            const int r0_ = 8 * w + 2 * q_;                                    \
            const int r_ = r0_ + (l >> 5);                                     \
            const int col_ = 4 * ((l & 31) ^ (r_ & 7));                        \
            const float* src_ = pb + (size_t)r_ * NHW + tb_ + col_;            \
            __builtin_amdgcn_global_load_lds(                                  \
                (const __attribute__((address_space(1))) unsigned*)src_,       \
                (__attribute__((address_space(3))) unsigned*)&buf[CUR][r0_][0],\
                16, 0, 0);                                                     \
        }                                                                      \
    }

#define LOADIDS(IV, MV, TB)                                                    \
    if (l < 16) {                                                              \
        (IV) = *(const int4*)(inst + img + (TB) + phalf * 64 + 4 * l);         \
        (MV) = *(const unsigned*)(msk + img + (TB) + phalf * 64 + 4 * l);      \
    }

#define DECODE(IV, MV, PK, VC)                                                 \
    if (l < 16) {                                                              \
        const int ia_[4] = {(IV).x, (IV).y, (IV).z, (IV).w};                   \
        (PK) = 0u;                                                             \
        _Pragma("unroll")                                                      \
        for (int p_ = 0; p_ < 4; ++p_) {                                       \
            const bool m_ = ((((MV) >> (8 * p_)) & 0xffu) != 0u) &&            \
                            (ia_[p_] != IGN);                                  \
            if (dgrp == 0) (VC) += m_ ? 1.f : 0.f;                             \
            const unsigned s_ =                                                \
                (m_ && (unsigned)ia_[p_] < NK) ? (unsigned)ia_[p_] : NK;       \
            (PK) |= s_ << (8 * p_);                                            \
        }                                                                      \
    }

    int4 iv; unsigned mv = 0;
    LOADIDS(iv, mv, base0);
    STAGE(0, 0);
    unsigned pk = 0;
    float vcnt = 0.f;
    DECODE(iv, mv, pk, vcnt);
    __syncthreads();

    f32x4 acc = {0.f, 0.f, 0.f, 0.f};
    for (int t = 0; t < NTILES; ++t) {
        const int cur = t & 1;
        const int tb = base0 + t * TILE;
        int4 iv2; unsigned mv2 = 0;
        if (t + 1 < NTILES) {
            LOADIDS(iv2, mv2, base0 + (t + 1) * TILE);
            STAGE(cur ^ 1, t + 1);
        }
        // bookkeeping for tile t (dgrp-0 waves, 16 lanes each)
        if (dgrp == 0 && l < 16) {
            uchar4 pkb = {(unsigned char)(pk & 0xff),
                          (unsigned char)((pk >> 8) & 0xff),
                          (unsigned char)((pk >> 16) & 0xff),
                          (unsigned char)(pk >> 24)};
            *(uchar4*)(idp + img + tb + phalf * 64 + 4 * l) = pkb;
            #pragma unroll
            for (int p = 0; p < 4; ++p)
                atomicAdd(&lcnt[phalf][(pk >> (8 * p)) & 0xffu], 1.f);
        }
        // consume tile t: 4 K-steps of 16 px over this wave's 64-px half
        #pragma unroll
        for (int kk = 0; kk < 4; ++kk) {
            const int row = dgrp * 16 + (l & 15);
            const int cb = phalf * 16 + kk * 4 + (l >> 4);
            const f32x4 av = *(const f32x4*)
                (&buf[cur][0][0] + row * TILE + 4 * (cb ^ (row & 7)));
            half4 ah;
            #pragma unroll
            for (int e = 0; e < 4; ++e) ah[e] = (_Float16)av[e];
            const int srcl = kk * 4 + (l >> 4);
            const unsigned pkk = (unsigned)__shfl((int)pk, srcl);
            half4 bh;
            #pragma unroll
            for (int e = 0; e < 4; ++e)
                bh[e] = (((pkk >> (8 * e)) & 0xffu) == (unsigned)(l & 15))
                            ? (_Float16)1.f : (_Float16)0.f;
            acc = __builtin_amdgcn_mfma_f32_16x16x16f16(ah, bh, acc, 0, 0, 0);
        }
        iv = iv2; mv = mv2;
        DECODE(iv, mv, pk, vcnt);
        __syncthreads();
    }
#undef STAGE
#undef LOADIDS
#undef DECODE

    // epilogue: acc[r] = sums_part[d = dgrp*16+4*(l>>4)+r][k = l&15] over phalf px
    float* sc = &buf[0][0][0];   // reuse staging: [4 widx][16 d][16 k]
    const int widx = dgrp * 2 + phalf;
    #pragma unroll
    for (int r = 0; r < 4; ++r)
        sc[(widx * 16 + 4 * (l >> 4) + r) * 16 + (l & 15)] = acc[r];
    __syncthreads();

    float* wb = ws + b * WS_S;
    for (int i = tid; i < NK * ND; i += ATPB) {   // i = k*32 + d
        const int k = i >> 5, d = i & 31, dg = d >> 4, dr = d & 15;
        const float v = sc[((dg * 2 + 0) * 16 + dr) * 16 + k] +
                        sc[((dg * 2 + 1) * 16 + dr) * 16 + k];
        atomicAdd(&wb[O_SUM + i], v);
    }
    if (tid < NK) atomicAdd(&wb[O_CNT + tid], lcnt[0][tid] + lcnt[1][tid]);
    if (w == 0 || w == 2) {
        #pragma unroll
        for (int off = 8; off > 0; off >>= 1) vcnt += __shfl_down(vcnt, off);
        if (l == 0) atomicAdd(&wb[O_VPIX], vcnt);
    }
}

// Pass 2: float4 streaming + packed ids; centers recomputed per block from ws.
__global__ __launch_bounds__(PTPB) void k_pull(const float* __restrict__ pred,
                                               const unsigned char* __restrict__ idp,
                                               float* __restrict__ ws) {
    __shared__ float lc[17][ND + 1];   // row 16 = zeros (invalid)
    __shared__ float lcc[NK];
    __shared__ float lp[2][NK];
    const int tid = threadIdx.x;
    // reversed global order vs k_accum: tail of pass-1 stream is L3-resident
    const int b = NB - 1 - blockIdx.y;
    const int chunk = PCHUNKS - 1 - blockIdx.x;
    const int half = (tid >> 5) & 1;
    float* wb = ws + b * WS_S;

    if (tid < NK) lcc[tid] = wb[O_CNT + tid];
    if (tid < 2 * NK) ((float*)lp)[tid] = 0.f;
    __syncthreads();
    for (int i = tid; i < 17 * ND; i += PTPB)
        lc[i >> 5][i & 31] =
            (i < NK * ND) ? wb[O_SUM + i] / fmaxf(lcc[i >> 5], 1.f) : 0.f;
    __syncthreads();

    const size_t img = (size_t)b * NHW;
    const float* pb = pred + (size_t)b * ND * NHW;

    const int pix = chunk * PPIX + 4 * tid;
    const unsigned pk = *(const unsigned*)(idp + img + pix);
    const int id[4] = {(int)(pk & 0xff), (int)((pk >> 8) & 0xff),
                       (int)((pk >> 16) & 0xff), (int)(pk >> 24)};
    float sq[4] = {0.f, 0.f, 0.f, 0.f};
    #pragma unroll 8
    for (int d = 0; d < ND; ++d) {
        const float4 v = *(const float4*)(pb + (size_t)d * NHW + pix);
        float df0 = v.x - lc[id[0]][d];
        float df1 = v.y - lc[id[1]][d];
        float df2 = v.z - lc[id[2]][d];
        float df3 = v.w - lc[id[3]][d];
        sq[0] += df0 * df0; sq[1] += df1 * df1;
        sq[2] += df2 * df2; sq[3] += df3 * df3;
    }
    #pragma unroll
    for (int p = 0; p < 4; ++p) {
        if (id[p] < NK) {
            float r = fmaxf(sqrtf(sq[p]) - 0.5f, 0.f);
            atomicAdd(&lp[half][id[p]], r * r);
        }
    }
    __syncthreads();
    if (tid < NK) atomicAdd(&wb[O_PULL + tid], lp[0][tid] + lp[1][tid]);
}

// Final: one wave; per-image centers->push/reg + pull/vb, then combine.
__global__ void k_final(const float* __restrict__ ws, float* __restrict__ out) {
    __shared__ float lc[NK][ND];
    __shared__ float lcc[NK];
    const int tid = threadIdx.x;  // 64 threads
    float total = 0.f, nvb = 0.f;

    for (int b = 0; b < NB; ++b) {
        const float* wb = ws + b * WS_S;
        if (tid < NK) lcc[tid] = wb[O_CNT + tid];
        __syncthreads();
        for (int i = tid; i < NK * ND; i += 64)
            lc[i >> 5][i & 31] = wb[O_SUM + i] / fmaxf(lcc[i >> 5], 1.f);
        __syncthreads();

        float nids_p = (tid < NK && lcc[tid] > 0.f) ? 1.f : 0.f;
        float pull_p = (tid < NK && lcc[tid] > 0.f)
                           ? wb[O_PULL + tid] / fmaxf(lcc[tid], 1.f) : 0.f;
        float reg_p = 0.f;
        if (tid < NK && lcc[tid] > 0.f) {
            float cs = 0.f;
            for (int d = 0; d < ND; ++d) cs += lc[tid][d] * lc[tid][d];
            reg_p = sqrtf(cs);
        }
        float push_p = 0.f;
        #pragma unroll
        for (int q = 0; q < 4; ++q) {   // 4 pairs per thread
            const int p = 4 * tid + q, i = p >> 4, j = p & 15;
            if (i != j && lcc[i] > 0.f && lcc[j] > 0.f) {
                float sq2 = 0.f;
                for (int d = 0; d < ND; ++d) {
                    float df = lc[i][d] - lc[j][d];
                    sq2 += df * df;
                }
                float r = fmaxf(3.f - sqrtf(sq2), 0.f);
                push_p += r * r;
            }
        }
        #pragma unroll
        for (int off = 32; off > 0; off >>= 1) {
            nids_p += __shfl_down(nids_p, off);
            pull_p += __shfl_down(pull_p, off);
            reg_p  += __shfl_down(reg_p, off);
            push_p += __shfl_down(push_p, off);
        }
        if (tid == 0) {
            const float nids = nids_p;
            const float pull = pull_p / fmaxf(nids, 1.f);
            const float npairs = nids * nids - nids;
            const float push =
                (nids > 1.f) ? push_p / fmaxf(npairs, 1.f) : 0.f;
            const float reg = reg_p / fmaxf(nids, 1.f);
            const float vb = (wb[O_VPIX] > 0.f) ? 1.f : 0.f;
            total += (pull + push + 0.001f * reg) * vb;
            nvb += vb;
        }
        __syncthreads();
    }
    if (tid == 0) out[0] = (nvb > 0.f) ? total / fmaxf(nvb, 1.f) : 0.f;
}

extern "C" void kernel_launch(void* const* d_in, const int* in_sizes, int n_in,
                              void* d_out, int out_size, void* d_ws, size_t ws_size,
                              hipStream_t stream) {
    const float* pred = (const float*)d_in[0];
    const int* inst = (const int*)d_in[1];
    const unsigned char* msk = (const unsigned char*)d_in[2];
    float* out = (float*)d_out;
    float* ws = (float*)d_ws;
    unsigned char* idp = (unsigned char*)d_ws + IDP_OFF;

    k_zero<<<(NB * WS_S + 255) / 256, 256, 0, stream>>>(ws);
    dim3 agrid(ABLK, NB);
    k_accum<<<agrid, ATPB, 0, stream>>>(pred, inst, msk, ws, idp);
    dim3 pgrid(PCHUNKS, NB);
    k_pull<<<pgrid, PTPB, 0, stream>>>(pred, idp, ws);
    k_final<<<1, 64, 0, stream>>>(ws, out);
}

// Round 7
// 135.519 us; speedup vs baseline: 1.0085x; 1.0085x over previous
//
#include <hip/hip_runtime.h>

typedef _Float16 half4 __attribute__((ext_vector_type(4)));
typedef float f32x4 __attribute__((ext_vector_type(4)));

#define NB 8
#define ND 32
#define NHW (512*512)
#define NK 16
#define IGN 255

// per-image stats workspace layout (floats)
#define WS_S   1088
#define O_CNT  0      // counts[16]
#define O_VPIX 16     // # of valid (mask & !=IGN) pixels
#define O_SUM  32     // sums[16*32], index = k*32 + d
#define O_PULL 1056   // pull partial sums[16]

#define IDP_OFF 65536          // byte offset of packed-id region in ws

// accum: 512 blocks (64/image), each 16 tiles of 256 px (4096 contiguous px).
// 4 waves/block; wave w owns pixel slice [64w, 64w+64) of every tile.
#define ATPB 256
#define ABLK 64
#define TILE 256
#define NTILES 16

// pull config
#define PTPB 256
#define PCHUNKS 256
#define PPIX (NHW / PCHUNKS)   // 1024

__global__ __launch_bounds__(256) void k_zero(float* __restrict__ ws) {
    int i = blockIdx.x * blockDim.x + threadIdx.x;
    if (i < NB * WS_S) ws[i] = 0.f;
}

// Pass 1: barrier-free staged streaming + MFMA one-hot segment-sum.
// Wave-private slices -> per-wave counted vmcnt only; no __syncthreads in loop.
__global__ __launch_bounds__(ATPB) void k_accum(const float* __restrict__ pred,
                                                const int* __restrict__ inst,
                                                const unsigned char* __restrict__ msk,
                                                float* __restrict__ ws,
                                                unsigned char* __restrict__ idp) {
    __shared__ __align__(16) float buf[2][4][ND][64];   // [dbuf][wave][d][px] 64 KB
    __shared__ float lcnt[4][20];                        // wave-private count rows
    const int tid = threadIdx.x;
    const int w = tid >> 6, l = tid & 63;
    const int lq = l >> 4, lr = l & 15;
    const int b = blockIdx.y, chunk = blockIdx.x;

    if (l < 20) lcnt[w][l] = 0.f;    // wave-private: no barrier needed

    const size_t img = (size_t)b * NHW;
    const float* pb = pred + (size_t)b * ND * NHW;
    const int base0 = chunk * (NTILES * TILE);
    const int sbase = 64 * w;        // wave's pixel offset within a tile

    // stage: 8 insts/wave/tile; inst q covers rows 4q..4q+3 of the wave's 64-px
    // slice. LDS dst linear; src pre-applies inverse XOR swizzle (chunk ^ row&15).
#define STAGE(CUR, T)                                                          \
    {                                                                          \
        const int tb_ = base0 + (T) * TILE + sbase;                            \
        _Pragma("unroll")                                                      \
        for (int q_ = 0; q_ < 8; ++q_) {                                       \
            const int r_ = 4 * q_ + lq;                                        \
            const float* src_ =                                                \
                pb + (size_t)r_ * NHW + tb_ + 4 * (lr ^ (r_ & 15));            \
            __builtin_amdgcn_global_load_lds(                                  \
                (const __attribute__((address_space(1))) unsigned*)src_,       \
                (__attribute__((address_space(3)))                             \
                     unsigned*)&buf[CUR][w][4 * q_][0],                        \
                16, 0, 0);                                                     \
        }                                                                      \
    }

#define LOADIDS(IV, MV, T)                                                     \
    if (l < 16) {                                                              \
        const int tb_ = base0 + (T) * TILE + sbase;                            \
        (IV) = *(const int4*)(inst + img + tb_ + 4 * l);                       \
        (MV) = *(const unsigned*)(msk + img + tb_ + 4 * l);                    \
    }

#define DECODE(IV, MV, PK)                                                     \
    if (l < 16) {                                                              \
        const int ia_[4] = {(IV).x, (IV).y, (IV).z, (IV).w};                   \
        (PK) = 0u;                                                             \
        _Pragma("unroll")                                                      \
        for (int p_ = 0; p_ < 4; ++p_) {                                       \
            const bool m_ = ((((MV) >> (8 * p_)) & 0xffu) != 0u) &&            \
                            (ia_[p_] != IGN);                                  \
            vcnt += m_ ? 1.f : 0.f;                                            \
            const unsigned s_ =                                                \
                (m_ && (unsigned)ia_[p_] < NK) ? (unsigned)ia_[p_] : NK;       \
            (PK) |= s_ << (8 * p_);                                            \
        }                                                                      \
    }

    float vcnt = 0.f;
    int4 iv; unsigned mv = 0;
    LOADIDS(iv, mv, 0);
    STAGE(0, 0);

    f32x4 acc0 = {0.f, 0.f, 0.f, 0.f};
    f32x4 acc1 = {0.f, 0.f, 0.f, 0.f};

    for (int t = 0; t < NTILES; ++t) {
        const int cur = t & 1;
        int4 iv2; unsigned mv2 = 0;
        if (t + 1 < NTILES) {
            LOADIDS(iv2, mv2, t + 1);          // 2 VMEM
            STAGE(cur ^ 1, t + 1);             // 8 VMEM
            asm volatile("s_waitcnt vmcnt(10)" ::: "memory");  // tile t ready
        } else {
            asm volatile("s_waitcnt vmcnt(0)" ::: "memory");
        }
        __builtin_amdgcn_sched_barrier(0);

        unsigned pk = 0;
        DECODE(iv, mv, pk);
        if (l < 16) {
            uchar4 pkb = {(unsigned char)(pk & 0xff),
                          (unsigned char)((pk >> 8) & 0xff),
                          (unsigned char)((pk >> 16) & 0xff),
                          (unsigned char)(pk >> 24)};
            *(uchar4*)(idp + img + base0 + t * TILE + sbase + 4 * l) = pkb;
            #pragma unroll
            for (int p = 0; p < 4; ++p)
                atomicAdd(&lcnt[w][(pk >> (8 * p)) & 0xffu], 1.f);
        }

        // consume tile t: 4 K-steps x 2 d-groups over the wave's 64 px
        const float* bufc = &buf[cur][w][0][0];
        #pragma unroll
        for (int kk = 0; kk < 4; ++kk) {
            const unsigned pkk = (unsigned)__shfl((int)pk, kk * 4 + lq);
            half4 bh;
            #pragma unroll
            for (int e = 0; e < 4; ++e)
                bh[e] = (((pkk >> (8 * e)) & 0xffu) == (unsigned)lr)
                            ? (_Float16)1.f : (_Float16)0.f;
            const int cb = (kk * 4 + lq) ^ lr;   // swizzled 4-float chunk
            const f32x4 av0 = *(const f32x4*)(bufc + (size_t)lr * 64 + 4 * cb);
            const f32x4 av1 =
                *(const f32x4*)(bufc + (size_t)(16 + lr) * 64 + 4 * cb);
            half4 ah0, ah1;
            #pragma unroll
            for (int e = 0; e < 4; ++e) {
                ah0[e] = (_Float16)av0[e];
                ah1[e] = (_Float16)av1[e];
            }
            acc0 = __builtin_amdgcn_mfma_f32_16x16x16f16(ah0, bh, acc0, 0, 0, 0);
            acc1 = __builtin_amdgcn_mfma_f32_16x16x16f16(ah1, bh, acc1, 0, 0, 0);
        }
        iv = iv2; mv = mv2;
    }
#undef STAGE
#undef LOADIDS
#undef DECODE

    // epilogue: acc{dg}[r] = sums_part[d = 16dg + 4*lq + r][k = lr] over wave px
    __syncthreads();
    float* sc = &buf[0][0][0][0];   // reuse: [w*2+dg][16 d][16 k]
    #pragma unroll
    for (int r = 0; r < 4; ++r) {
        sc[((w * 2 + 0) * 16 + 4 * lq + r) * 16 + lr] = acc0[r];
        sc[((w * 2 + 1) * 16 + 4 * lq + r) * 16 + lr] = acc1[r];
    }
    __syncthreads();

    float* wb = ws + b * WS_S;
    for (int i = tid; i < NK * ND; i += ATPB) {   // i = k*32 + d
        const int k = i >> 5, d = i & 31, dg = d >> 4, dr = d & 15;
        float v = 0.f;
        #pragma unroll
        for (int ww = 0; ww < 4; ++ww)
            v += sc[((ww * 2 + dg) * 16 + dr) * 16 + k];
        atomicAdd(&wb[O_SUM + i], v);
    }
    if (tid < NK)
        atomicAdd(&wb[O_CNT + tid],
                  lcnt[0][tid] + lcnt[1][tid] + lcnt[2][tid] + lcnt[3][tid]);
    #pragma unroll
    for (int off = 8; off > 0; off >>= 1) vcnt += __shfl_down(vcnt, off);
    if (l == 0) atomicAdd(&wb[O_VPIX], vcnt);
}

// Pass 2: float4 streaming + packed ids; centers recomputed per block from ws.
__global__ __launch_bounds__(PTPB) void k_pull(const float* __restrict__ pred,
                                               const unsigned char* __restrict__ idp,
                                               float* __restrict__ ws) {
    __shared__ float lc[17][ND + 1];   // row 16 = zeros (invalid)
    __shared__ float lcc[NK];
    __shared__ float lp[2][NK];
    const int tid = threadIdx.x;
    // reversed global order vs k_accum: tail of pass-1 stream is L3-resident
    const int b = NB - 1 - blockIdx.y;
    const int chunk = PCHUNKS - 1 - blockIdx.x;
    const int half = (tid >> 5) & 1;
    float* wb = ws + b * WS_S;

    if (tid < NK) lcc[tid] = wb[O_CNT + tid];
    if (tid < 2 * NK) ((float*)lp)[tid] = 0.f;
    __syncthreads();
    for (int i = tid; i < 17 * ND; i += PTPB)
        lc[i >> 5][i & 31] =
            (i < NK * ND) ? wb[O_SUM + i] / fmaxf(lcc[i >> 5], 1.f) : 0.f;
    __syncthreads();

    const size_t img = (size_t)b * NHW;
    const float* pb = pred + (size_t)b * ND * NHW;

    const int pix = chunk * PPIX + 4 * tid;
    const unsigned pk = *(const unsigned*)(idp + img + pix);
    const int id[4] = {(int)(pk & 0xff), (int)((pk >> 8) & 0xff),
                       (int)((pk >> 16) & 0xff), (int)(pk >> 24)};
    float sq[4] = {0.f, 0.f, 0.f, 0.f};
    #pragma unroll 8
    for (int d = 0; d < ND; ++d) {
        const float4 v = *(const float4*)(pb + (size_t)d * NHW + pix);
        float df0 = v.x - lc[id[0]][d];
        float df1 = v.y - lc[id[1]][d];
        float df2 = v.z - lc[id[2]][d];
        float df3 = v.w - lc[id[3]][d];
        sq[0] += df0 * df0; sq[1] += df1 * df1;
        sq[2] += df2 * df2; sq[3] += df3 * df3;
    }
    #pragma unroll
    for (int p = 0; p < 4; ++p) {
        if (id[p] < NK) {
            float r = fmaxf(sqrtf(sq[p]) - 0.5f, 0.f);
            atomicAdd(&lp[half][id[p]], r * r);
        }
    }
    __syncthreads();
    if (tid < NK) atomicAdd(&wb[O_PULL + tid], lp[0][tid] + lp[1][tid]);
}

// Final: one wave; per-image centers->push/reg + pull/vb, then combine.
__global__ void k_final(const float* __restrict__ ws, float* __restrict__ out) {
    __shared__ float lc[NK][ND];
    __shared__ float lcc[NK];
    const int tid = threadIdx.x;  // 64 threads
    float total = 0.f, nvb = 0.f;

    for (int b = 0; b < NB; ++b) {
        const float* wb = ws + b * WS_S;
        if (tid < NK) lcc[tid] = wb[O_CNT + tid];
        __syncthreads();
        for (int i = tid; i < NK * ND; i += 64)
            lc[i >> 5][i & 31] = wb[O_SUM + i] / fmaxf(lcc[i >> 5], 1.f);
        __syncthreads();

        float nids_p = (tid < NK && lcc[tid] > 0.f) ? 1.f : 0.f;
        float pull_p = (tid < NK && lcc[tid] > 0.f)
                           ? wb[O_PULL + tid] / fmaxf(lcc[tid], 1.f) : 0.f;
        float reg_p = 0.f;
        if (tid < NK && lcc[tid] > 0.f) {
            float cs = 0.f;
            for (int d = 0; d < ND; ++d) cs += lc[tid][d] * lc[tid][d];
            reg_p = sqrtf(cs);
        }
        float push_p = 0.f;
        #pragma unroll
        for (int q = 0; q < 4; ++q) {   // 4 pairs per thread
            const int p = 4 * tid + q, i = p >> 4, j = p & 15;
            if (i != j && lcc[i] > 0.f && lcc[j] > 0.f) {
                float sq2 = 0.f;
                for (int d = 0; d < ND; ++d) {
                    float df = lc[i][d] - lc[j][d];
                    sq2 += df * df;
                }
                float r = fmaxf(3.f - sqrtf(sq2), 0.f);
                push_p += r * r;
            }
        }
        #pragma unroll
        for (int off = 32; off > 0; off >>= 1) {
            nids_p += __shfl_down(nids_p, off);
            pull_p += __shfl_down(pull_p, off);
            reg_p  += __shfl_down(reg_p, off);
            push_p += __shfl_down(push_p, off);
        }
        if (tid == 0) {
            const float nids = nids_p;
            const float pull = pull_p / fmaxf(nids, 1.f);
            const float npairs = nids * nids - nids;
            const float push =
                (nids > 1.f) ? push_p / fmaxf(npairs, 1.f) : 0.f;
            const float reg = reg_p / fmaxf(nids, 1.f);
            const float vb = (wb[O_VPIX] > 0.f) ? 1.f : 0.f;
            total += (pull + push + 0.001f * reg) * vb;
            nvb += vb;
        }
        __syncthreads();
    }
    if (tid == 0) out[0] = (nvb > 0.f) ? total / fmaxf(nvb, 1.f) : 0.f;
}

extern "C" void kernel_launch(void* const* d_in, const int* in_sizes, int n_in,
                              void* d_out, int out_size, void* d_ws, size_t ws_size,
                              hipStream_t stream) {
    const float* pred = (const float*)d_in[0];
    const int* inst = (const int*)d_in[1];
    const unsigned char* msk = (const unsigned char*)d_in[2];
    float* out = (float*)d_out;
    float* ws = (float*)d_ws;
    unsigned char* idp = (unsigned char*)d_ws + IDP_OFF;

    k_zero<<<(NB * WS_S + 255) / 256, 256, 0, stream>>>(ws);
    dim3 agrid(ABLK, NB);
    k_accum<<<agrid, ATPB, 0, stream>>>(pred, inst, msk, ws, idp);
    dim3 pgrid(PCHUNKS, NB);
    k_pull<<<pgrid, PTPB, 0, stream>>>(pred, idp, ws);
    k_final<<<1, 64, 0, stream>>>(ws, out);
}